// Round 1
// baseline (237.114 us; speedup 1.0000x reference)
//
#include <hip/hip_runtime.h>
#include <hip/hip_bf16.h>

// Problem: B=4096, L=50, D=64, E=128, CAT=384, U=256, V=100000
// Dtypes per reference: ALL float tensors fp32, ids/mask int32, out fp32 [B,E].
//
// Factored algebra: h = relu(q·W_q + k·W_k + (q*k)·W_qk + b_hide)
//   qv[u] = q·W_q[:,u] + b_hide[u]   (fp32 VALU, split-K over 2 thread-halves)
//   GEMM per b: [64pad x 256] x [256 x 256], A=[K | K*q] bf16, B=[W_k;W_qk] bf16
// scores = (h·W_out + b_out) * mask ; out[b] = scores · K   (fp32)
//
// V2 change vs V1 (139us/dispatch): latency/occupancy-bound (all pipes <17%).
// Occupancy was register-capped: acc[4][4]=64 AGPR + operands ~144 total regs
// -> 3 waves/SIMD -> 12 waves/CU. Now 8 waves/block, N=32/wave: acc[4][2]=32
// -> target <=85 total regs -> 6 waves/SIMD -> 24 waves/CU (3 blocks x 8 waves).
// Algorithm, LDS layout, and all rounding points are IDENTICAL to V1.

#define L_SEQ 50
#define LP    64
#define D_EMB 64
#define E_DIM 128
#define U_DIM 256
#define CATK  384
#define V_SZ  100000
#define KSTR  136   // LDS row stride (bf16 elems): 16B-aligned rows, 2-way-free banks

typedef __bf16 bf16x4 __attribute__((ext_vector_type(4)));
typedef __bf16 bf16x8 __attribute__((ext_vector_type(8)));
typedef float  f32x4  __attribute__((ext_vector_type(4)));

// module-owned: g_Wt[n][kk] = bf16(W_hide[kk][n]), 256x384 bf16 = 192 KB
__device__ __bf16 g_Wt[U_DIM * CATK];

// ---- prep: transpose+cast W_hide fp32 [384][256] -> g_Wt bf16 [256][384] ----
__global__ __launch_bounds__(256) void wt_transpose_kernel(
    const float* __restrict__ W_hide) {
  __shared__ __bf16 tile[64][72];
  const int bc = blockIdx.x % 6, bu = blockIdx.x / 6;   // c-tile 0..5, u-tile 0..3
  const int tx = threadIdx.x & 63, ty = threadIdx.x >> 6;
  for (int i = 0; i < 64; i += 4) {
    int c = bc * 64 + i + ty;          // 0..383
    int u = bu * 64 + tx;              // 0..255
    tile[i + ty][tx] = (__bf16)W_hide[c * 256 + u];   // coalesced fp32 read
  }
  __syncthreads();
  for (int i = 0; i < 64; i += 4) {
    int u = bu * 64 + i + ty;
    int c = bc * 64 + tx;
    g_Wt[u * CATK + c] = tile[tx][i + ty];
  }
}

// ---- main: one block (8 waves, 512 threads) per b ----
__global__ __launch_bounds__(512, 6) void din_main_kernel(
    const int* __restrict__ qid_item, const int* __restrict__ qid_cate,
    const int* __restrict__ seq_item, const int* __restrict__ seq_cate,
    const int* __restrict__ mask,
    const float* __restrict__ emb_item,
    const float* __restrict__ emb_cate,
    const float* __restrict__ b_hide,  // [256]
    const float* __restrict__ W_out,   // [256]
    const float* __restrict__ b_out,   // [1]
    float* __restrict__ out) {
  __shared__ alignas(16) __bf16 Kb[LP * KSTR];   // bf16(K)
  __shared__ alignas(16) __bf16 A2[LP * KSTR];   // bf16(K*q)
  __shared__ alignas(16) float qrowf[E_DIM];     // fp32 q
  __shared__ float qv2[2][U_DIM];                // split-K partials of qv
  __shared__ float mask_f[LP];
  __shared__ float scpart[8][LP];
  __shared__ float scores[LP];

  const int b = blockIdx.x;
  const int t = threadIdx.x;
  const int r = t >> 3, c8 = t & 7;   // row 0..63, col-chunk of 16 floats
  const int col0 = c8 * 16;           // this thread's 16 columns of [item|cate]

  // ---- phase 1: gather K rows (fp32) into regs, cast to LDS bf16 ----
  float4 kv[4];
  if (r < L_SEQ) {
    int id = (c8 < 4) ? seq_item[b * L_SEQ + r] : seq_cate[b * L_SEQ + r];
    if ((unsigned)id >= (unsigned)V_SZ) id = 0;   // insurance
    const float4* s4 = (const float4*)(((c8 < 4) ? emb_item : emb_cate)
                                       + (size_t)id * D_EMB + (c8 & 3) * 16);
#pragma unroll
    for (int i = 0; i < 4; ++i) kv[i] = s4[i];
  } else {
#pragma unroll
    for (int i = 0; i < 4; ++i) kv[i] = make_float4(0.f, 0.f, 0.f, 0.f);
  }
#pragma unroll
  for (int i = 0; i < 4; ++i) {
    bf16x4 h4 = {(__bf16)kv[i].x, (__bf16)kv[i].y, (__bf16)kv[i].z, (__bf16)kv[i].w};
    *(bf16x4*)&Kb[r * KSTR + col0 + i * 4] = h4;   // 8B store, aligned
  }
  if (t < 8) {   // q row: 8 threads x 16 floats
    int id = (t < 4) ? qid_item[b] : qid_cate[b];
    if ((unsigned)id >= (unsigned)V_SZ) id = 0;
    const float4* s4 = (const float4*)(((t < 4) ? emb_item : emb_cate)
                                       + (size_t)id * D_EMB + (t & 3) * 16);
    float4* d4 = (float4*)&qrowf[t * 16];
#pragma unroll
    for (int i = 0; i < 4; ++i) d4[i] = s4[i];
  }
  if (t < LP) mask_f[t] = (t < L_SEQ && mask[b * L_SEQ + t] != 0) ? 1.0f : 0.0f;
  __syncthreads();

  // ---- phase 2: A2 = bf16(K * q) from fp32 regs (single rounding) ----
#pragma unroll
  for (int i = 0; i < 4; ++i) {
    const float* qp = &qrowf[col0 + i * 4];
    bf16x4 h4 = {(__bf16)(kv[i].x * qp[0]), (__bf16)(kv[i].y * qp[1]),
                 (__bf16)(kv[i].z * qp[2]), (__bf16)(kv[i].w * qp[3])};
    *(bf16x4*)&A2[r * KSTR + col0 + i * 4] = h4;
  }
  __syncthreads();

  // ---- phase 3a: qv2[half][u] = partial of b_hide[u] + q·W_q[:,u] ----
  {
    const int u = t & 255, half = t >> 8;
    const int cbase = half * 64;
    float acc_q = half ? 0.f : b_hide[u];
#pragma unroll
    for (int c8i = 0; c8i < 8; ++c8i) {
      bf16x8 w = *(const bf16x8*)&g_Wt[u * CATK + cbase + c8i * 8];   // W_q^T slice
#pragma unroll
      for (int j = 0; j < 8; ++j)
        acc_q += qrowf[cbase + c8i * 8 + j] * (float)w[j];
    }
    qv2[half][u] = acc_q;
  }

  // ---- phase 3b: MFMA. M=64 (4 tiles), N=32/wave (2 tiles), K=256 (8 steps) ----
  const int wave = t >> 6, lane = t & 63;
  const int m = lane & 15, quad = lane >> 4;
  f32x4 acc[4][2];
#pragma unroll
  for (int mt = 0; mt < 4; ++mt)
#pragma unroll
    for (int nt = 0; nt < 2; ++nt) acc[mt][nt] = (f32x4){0.f, 0.f, 0.f, 0.f};

#pragma unroll
  for (int s = 0; s < 8; ++s) {
    const __bf16* Ab = (s < 4) ? Kb : A2;
    const int klocal = (s & 3) * 32 + quad * 8;
    const int kglob  = s * 32 + quad * 8;       // k in [0,256) of [W_k;W_qk]
    bf16x8 afr[4], bfr[2];
#pragma unroll
    for (int mt = 0; mt < 4; ++mt)
      afr[mt] = *(const bf16x8*)&Ab[(mt * 16 + m) * KSTR + klocal];
#pragma unroll
    for (int nt = 0; nt < 2; ++nt) {
      int n = wave * 32 + nt * 16 + m;
      bfr[nt] = *(const bf16x8*)&g_Wt[n * CATK + 128 + kglob];  // skip W_q slice
    }
#pragma unroll
    for (int mt = 0; mt < 4; ++mt)
#pragma unroll
      for (int nt = 0; nt < 2; ++nt)
        acc[mt][nt] = __builtin_amdgcn_mfma_f32_16x16x32_bf16(
            afr[mt], bfr[nt], acc[mt][nt], 0, 0, 0);
  }
  __syncthreads();   // qv2 ready for cross-thread reads

  // ---- epilogue: h = relu(acc + qv[n]); partial score = h·W_out ----
  float qv[2], wo[2];
#pragma unroll
  for (int nt = 0; nt < 2; ++nt) {
    int n = wave * 32 + nt * 16 + m;
    qv[nt] = qv2[0][n] + qv2[1][n];
    wo[nt] = W_out[n];
  }
  float part[16];   // rows mt*16 + quad*4 + rg
#pragma unroll
  for (int mt = 0; mt < 4; ++mt)
#pragma unroll
    for (int rg = 0; rg < 4; ++rg) {
      float sum = 0.f;
#pragma unroll
      for (int nt = 0; nt < 2; ++nt) {
        float h = acc[mt][nt][rg] + qv[nt];
        h = fmaxf(h, 0.f);
        sum += h * wo[nt];
      }
      part[mt * 4 + rg] = sum;
    }
  // reduce across the 16 lanes (m=0..15) holding the same rows
#pragma unroll
  for (int off = 1; off < 16; off <<= 1)
#pragma unroll
    for (int i = 0; i < 16; ++i)
      part[i] += __shfl_xor(part[i], off, 64);
  if (m == 0) {
#pragma unroll
    for (int mt = 0; mt < 4; ++mt)
#pragma unroll
      for (int rg = 0; rg < 4; ++rg)
        scpart[wave][mt * 16 + quad * 4 + rg] = part[mt * 4 + rg];
  }
  __syncthreads();
  if (t < LP) {
    float s = scpart[0][t] + scpart[1][t] + scpart[2][t] + scpart[3][t]
            + scpart[4][t] + scpart[5][t] + scpart[6][t] + scpart[7][t]
            + b_out[0];
    scores[t] = s * mask_f[t];
  }
  __syncthreads();
  // out[b][e] = sum_l scores[l] * K[l][e]   (fp32 out)
  if (t < E_DIM) {
    float o = 0.f;
    for (int l = 0; l < L_SEQ; ++l)
      o += scores[l] * (float)Kb[l * KSTR + t];
    out[(size_t)b * E_DIM + t] = o;
  }
}

extern "C" void kernel_launch(void* const* d_in, const int* in_sizes, int n_in,
                              void* d_out, int out_size, void* d_ws, size_t ws_size,
                              hipStream_t stream) {
  const int* qid_item = (const int*)d_in[0];
  const int* qid_cate = (const int*)d_in[1];
  const int* seq_item = (const int*)d_in[2];
  const int* seq_cate = (const int*)d_in[3];
  const int* mask     = (const int*)d_in[4];
  const float* emb_item = (const float*)d_in[5];
  const float* emb_cate = (const float*)d_in[6];
  const float* W_hide   = (const float*)d_in[7];
  const float* b_hide   = (const float*)d_in[8];
  const float* W_out    = (const float*)d_in[9];
  const float* b_out    = (const float*)d_in[10];
  float* out = (float*)d_out;

  (void)d_ws; (void)ws_size;  // intentionally unused

  wt_transpose_kernel<<<24, 256, 0, stream>>>(W_hide);
  din_main_kernel<<<4096, 512, 0, stream>>>(qid_item, qid_cate, seq_item, seq_cate,
                                            mask, emb_item, emb_cate,
                                            b_hide, W_out, b_out, out);
}

// Round 2
// 232.406 us; speedup vs baseline: 1.0203x; 1.0203x over previous
//
#include <hip/hip_runtime.h>
#include <hip/hip_bf16.h>

// Problem: B=4096, L=50, D=64, E=128, CAT=384, U=256, V=100000
// Dtypes per reference: ALL float tensors fp32, ids/mask int32, out fp32 [B,E].
//
// Factored algebra: h = relu(q·W_q + k·W_k + (q*k)·W_qk + b_hide)
//   qv[u] = q·W_q[:,u] + b_hide[u]   (fp32 VALU phase — parallel pipe to LDS)
//   GEMM per b: swapped operands C[u,l] = (W·A^T): A-op = [W_k;W_qk] rows (global),
//   B-op = [K | K*q] rows (LDS).  C layout: col(lane&15)=l, row(quad*4+reg)=u.
// scores = (relu(C+qv)·W_out + b_out) * mask ; out[b] = scores · K   (fp32)
//
// V3 vs V1(139us)/V2(170us): V2 proved occupancy is NOT the bottleneck; DS-pipe
// accounting shows LDS ~35% of wall (largest pipe), dominated by the 64
// ds_bpermute/wave epilogue reduction + scalar final loop. Operand swap makes
// the u-reduction in-lane: 8 bpermutes/wave (quad-reduce only). Final scores·K
// made wave-parallel with b32 pair reads. All loads identical to V1 (proven
// layouts); only mfma arg order + epilogue indexing change.

#define L_SEQ 50
#define LP    64
#define D_EMB 64
#define E_DIM 128
#define U_DIM 256
#define CATK  384
#define V_SZ  100000
#define KSTR  136   // LDS row stride (bf16): 272B = 17*16B -> bank rotation by 4/row

typedef __bf16 bf16x2 __attribute__((ext_vector_type(2)));
typedef __bf16 bf16x4 __attribute__((ext_vector_type(4)));
typedef __bf16 bf16x8 __attribute__((ext_vector_type(8)));
typedef float  f32x4  __attribute__((ext_vector_type(4)));

// module-owned: g_Wt[n][kk] = bf16(W_hide[kk][n]), 256x384 bf16 = 192 KB
__device__ __bf16 g_Wt[U_DIM * CATK];

// ---- prep: transpose+cast W_hide fp32 [384][256] -> g_Wt bf16 [256][384] ----
__global__ __launch_bounds__(256) void wt_transpose_kernel(
    const float* __restrict__ W_hide) {
  __shared__ __bf16 tile[64][72];
  const int bc = blockIdx.x % 6, bu = blockIdx.x / 6;   // c-tile 0..5, u-tile 0..3
  const int tx = threadIdx.x & 63, ty = threadIdx.x >> 6;
  for (int i = 0; i < 64; i += 4) {
    int c = bc * 64 + i + ty;          // 0..383
    int u = bu * 64 + tx;              // 0..255
    tile[i + ty][tx] = (__bf16)W_hide[c * 256 + u];   // coalesced fp32 read
  }
  __syncthreads();
  for (int i = 0; i < 64; i += 4) {
    int u = bu * 64 + i + ty;
    int c = bc * 64 + tx;
    g_Wt[u * CATK + c] = tile[tx][i + ty];
  }
}

// ---- main: one block (4 waves, 256 threads) per b ----
__global__ __launch_bounds__(256) void din_main_kernel(
    const int* __restrict__ qid_item, const int* __restrict__ qid_cate,
    const int* __restrict__ seq_item, const int* __restrict__ seq_cate,
    const int* __restrict__ mask,
    const float* __restrict__ emb_item,
    const float* __restrict__ emb_cate,
    const float* __restrict__ b_hide,  // [256]
    const float* __restrict__ W_out,   // [256]
    const float* __restrict__ b_out,   // [1]
    float* __restrict__ out) {
  __shared__ alignas(16) __bf16 Kb[LP * KSTR];   // bf16(K)
  __shared__ alignas(16) __bf16 A2[LP * KSTR];   // bf16(K*q)
  __shared__ alignas(16) float qrowf[E_DIM];     // fp32 q
  __shared__ alignas(16) float qv_s[U_DIM];      // b_hide + q·W_q
  __shared__ float mask_f[LP];
  __shared__ float scpart[4][LP];                // per-wave u-partial scores
  __shared__ float scores_s[LP];
  __shared__ float outp[4][E_DIM];               // per-wave l-partial outputs

  const int b = blockIdx.x;
  const int t = threadIdx.x;
  const int r = t >> 2, q4 = t & 3;
  const int col0 = q4 * 32;   // this thread's 32 columns of [item|cate]

  // ---- phase 1: gather K rows (fp32) into regs, cast to LDS bf16 ----
  float4 kv[8];
  if (r < L_SEQ) {
    int id = (q4 < 2) ? seq_item[b * L_SEQ + r] : seq_cate[b * L_SEQ + r];
    if ((unsigned)id >= (unsigned)V_SZ) id = 0;   // insurance
    const float4* s4 = (const float4*)(((q4 < 2) ? emb_item : emb_cate)
                                       + (size_t)id * D_EMB + (q4 & 1) * 32);
#pragma unroll
    for (int i = 0; i < 8; ++i) kv[i] = s4[i];
  } else {
#pragma unroll
    for (int i = 0; i < 8; ++i) kv[i] = make_float4(0.f, 0.f, 0.f, 0.f);
  }
#pragma unroll
  for (int i = 0; i < 8; ++i) {
    bf16x4 h4 = {(__bf16)kv[i].x, (__bf16)kv[i].y, (__bf16)kv[i].z, (__bf16)kv[i].w};
    *(bf16x4*)&Kb[r * KSTR + col0 + i * 4] = h4;   // 8B store, aligned
  }
  if (t < 4) {   // q row: 4 threads x 32 floats
    int id = (t < 2) ? qid_item[b] : qid_cate[b];
    if ((unsigned)id >= (unsigned)V_SZ) id = 0;
    const float4* s4 = (const float4*)(((t < 2) ? emb_item : emb_cate)
                                       + (size_t)id * D_EMB + (t & 1) * 32);
    float4* d4 = (float4*)&qrowf[t * 32];
#pragma unroll
    for (int i = 0; i < 8; ++i) d4[i] = s4[i];
  }
  if (t < LP) mask_f[t] = (t < L_SEQ && mask[b * L_SEQ + t] != 0) ? 1.0f : 0.0f;
  __syncthreads();

  // ---- phase 2: A2 = bf16(K * q) from fp32 regs (single rounding) ----
#pragma unroll
  for (int i = 0; i < 8; ++i) {
    const float* qp = &qrowf[col0 + i * 4];
    bf16x4 h4 = {(__bf16)(kv[i].x * qp[0]), (__bf16)(kv[i].y * qp[1]),
                 (__bf16)(kv[i].z * qp[2]), (__bf16)(kv[i].w * qp[3])};
    *(bf16x4*)&A2[r * KSTR + col0 + i * 4] = h4;
  }
  __syncthreads();

  // ---- phase 3a: qv_s[u=t] = b_hide[u] + sum_c q[c]*W_q[c][u] (fp32 VALU) ----
  {
    float acc_q = b_hide[t];
#pragma unroll
    for (int c8 = 0; c8 < 16; ++c8) {
      bf16x8 w = *(const bf16x8*)&g_Wt[t * CATK + c8 * 8];   // W_q^T slice
#pragma unroll
      for (int j = 0; j < 8; ++j)
        acc_q += qrowf[c8 * 8 + j] * (float)w[j];
    }
    qv_s[t] = acc_q;
  }

  // ---- phase 3b: swapped MFMA. M=u (64/wave, 4 tiles), N=l (64, 4 tiles),
  //      K=256 (8 steps). A-op = g_Wt rows (global), B-op = Kb/A2 rows (LDS).
  const int wave = t >> 6, lane = t & 63;
  const int m = lane & 15, quad = lane >> 4;
  f32x4 acc[4][4];
#pragma unroll
  for (int mt = 0; mt < 4; ++mt)
#pragma unroll
    for (int nt = 0; nt < 4; ++nt) acc[mt][nt] = (f32x4){0.f, 0.f, 0.f, 0.f};

#pragma unroll
  for (int s = 0; s < 8; ++s) {
    const __bf16* Bb = (s < 4) ? Kb : A2;
    const int klocal = (s & 3) * 32 + quad * 8;
    const int kglob  = s * 32 + quad * 8;       // k in [0,256) of [W_k;W_qk]
    bf16x8 wfr[4], kfr[4];
#pragma unroll
    for (int mt = 0; mt < 4; ++mt) {
      int u = wave * 64 + mt * 16 + m;
      wfr[mt] = *(const bf16x8*)&g_Wt[u * CATK + 128 + kglob];  // skip W_q slice
    }
#pragma unroll
    for (int nt = 0; nt < 4; ++nt)
      kfr[nt] = *(const bf16x8*)&Bb[(nt * 16 + m) * KSTR + klocal];
#pragma unroll
    for (int mt = 0; mt < 4; ++mt)
#pragma unroll
      for (int nt = 0; nt < 4; ++nt)
        acc[mt][nt] = __builtin_amdgcn_mfma_f32_16x16x32_bf16(
            wfr[mt], kfr[nt], acc[mt][nt], 0, 0, 0);
  }
  __syncthreads();   // qv_s ready for cross-thread reads

  // ---- epilogue: C[u,l]: u = wave*64+mt*16+quad*4+rg (in-lane), l = nt*16+m.
  //      part[nt] = sum_u relu(C+qv[u])*W_out[u]  — u-reduce is in-lane + quads.
  float qv4[4][4], wo4[4][4];
#pragma unroll
  for (int mt = 0; mt < 4; ++mt) {
    const int u0 = wave * 64 + mt * 16 + quad * 4;
    f32x4 qq = *(const f32x4*)&qv_s[u0];        // broadcast b128 (lane-uniform/16)
    float4 ww = *(const float4*)&W_out[u0];     // L1-resident global
    qv4[mt][0] = qq[0]; qv4[mt][1] = qq[1]; qv4[mt][2] = qq[2]; qv4[mt][3] = qq[3];
    wo4[mt][0] = ww.x;  wo4[mt][1] = ww.y;  wo4[mt][2] = ww.z;  wo4[mt][3] = ww.w;
  }
  float part[4];
#pragma unroll
  for (int nt = 0; nt < 4; ++nt) {
    float sum = 0.f;
#pragma unroll
    for (int mt = 0; mt < 4; ++mt)
#pragma unroll
      for (int rg = 0; rg < 4; ++rg) {
        float h = acc[mt][nt][rg] + qv4[mt][rg];
        h = fmaxf(h, 0.f);
        sum += h * wo4[mt][rg];
      }
    part[nt] = sum;
  }
#pragma unroll
  for (int nt = 0; nt < 4; ++nt) {   // reduce over 4 quads: 2 bpermutes each
    part[nt] += __shfl_xor(part[nt], 16, 64);
    part[nt] += __shfl_xor(part[nt], 32, 64);
  }
  if (lane < 16) {
#pragma unroll
    for (int nt = 0; nt < 4; ++nt)
      scpart[wave][nt * 16 + lane] = part[nt];   // l = nt*16+lane
  }
  __syncthreads();

  // ---- scores (t<64), then wave-parallel out partials ----
  if (t < LP) {
    float s = scpart[0][t] + scpart[1][t] + scpart[2][t] + scpart[3][t]
            + b_out[0];
    scores_s[t] = s * mask_f[t];
  }
  __syncthreads();
  // wave w accumulates rows [w*16, w*16+16); lane covers e = 2*lane, 2*lane+1
  {
    const int e2 = lane * 2;
    float o0 = 0.f, o1 = 0.f;
#pragma unroll
    for (int i = 0; i < 16; ++i) {
      const int l = wave * 16 + i;
      const float sc = scores_s[l];                       // broadcast
      bf16x2 kk = *(const bf16x2*)&Kb[l * KSTR + e2];     // b32 pair, 2-way banks
      o0 += sc * (float)kk[0];
      o1 += sc * (float)kk[1];
    }
    outp[wave][e2]     = o0;
    outp[wave][e2 + 1] = o1;
  }
  __syncthreads();
  if (t < E_DIM) {
    float o = outp[0][t] + outp[1][t] + outp[2][t] + outp[3][t];
    out[(size_t)b * E_DIM + t] = o;
  }
}

extern "C" void kernel_launch(void* const* d_in, const int* in_sizes, int n_in,
                              void* d_out, int out_size, void* d_ws, size_t ws_size,
                              hipStream_t stream) {
  const int* qid_item = (const int*)d_in[0];
  const int* qid_cate = (const int*)d_in[1];
  const int* seq_item = (const int*)d_in[2];
  const int* seq_cate = (const int*)d_in[3];
  const int* mask     = (const int*)d_in[4];
  const float* emb_item = (const float*)d_in[5];
  const float* emb_cate = (const float*)d_in[6];
  const float* W_hide   = (const float*)d_in[7];
  const float* b_hide   = (const float*)d_in[8];
  const float* W_out    = (const float*)d_in[9];
  const float* b_out    = (const float*)d_in[10];
  float* out = (float*)d_out;

  (void)d_ws; (void)ws_size;  // intentionally unused

  wt_transpose_kernel<<<24, 256, 0, stream>>>(W_hide);
  din_main_kernel<<<4096, 256, 0, stream>>>(qid_item, qid_cate, seq_item, seq_cate,
                                            mask, emb_item, emb_cate,
                                            b_hide, W_out, b_out, out);
}

// Round 3
// 161.653 us; speedup vs baseline: 1.4668x; 1.4377x over previous
//
#include <hip/hip_runtime.h>
#include <hip/hip_bf16.h>

// Problem: B=4096, L=50, D=64, E=128, CAT=384, U=256, V=100000
// Dtypes per reference: ALL float tensors fp32, ids/mask int32, out fp32 [B,E].
//
// Factored algebra: h = relu(q·W_q + k·W_k + (q*k)·W_qk + b_hide)
//   qv[u] = q·W_q[:,u] + b_hide[u]   (fp32 VALU, split-K halves, coalesced W_q)
//   GEMM per b: swapped operands C[u,l]: A-op = W rows (global, FRAGMENT-ORDERED),
//   B-op = [K | K*q] rows (LDS).  C layout: col(lane&15)=l, row(quad*4+reg)=u.
// scores = (relu(C+qv)·W_out + b_out) * mask ; out[b] = scores · K   (fp32)
//
// V4 vs V1-V3 (139-151us, invariant to occupancy and DS work): the hidden serial
// resource was TA line-requests from uncoalesced g_Wt^T reads (u carries lane&15
// at 768B stride -> ~64 lines per load instr; ~12K line-ops/block ~= the wall).
// Fix: prep writes W in per-lane FRAGMENT ORDER (g_W3) so wfr loads are
// lane-consecutive 16B (16 lines/instr, minimal), and a c-major W_q copy
// (g_Wq_c) so the qv phase reads lane-consecutive bf16x2. Fragment byte values
// are bit-identical to V3 -> numerics unchanged (qv split-K reorder: V2
// precedent, same absmax).

#define L_SEQ 50
#define LP    64
#define D_EMB 64
#define E_DIM 128
#define U_DIM 256
#define CATK  384
#define V_SZ  100000
#define KSTR  136   // LDS row stride (bf16): 272B = 17*16B -> bank rotation by 4/row

typedef __bf16 bf16x2 __attribute__((ext_vector_type(2)));
typedef __bf16 bf16x4 __attribute__((ext_vector_type(4)));
typedef __bf16 bf16x8 __attribute__((ext_vector_type(8)));
typedef float  f32x4  __attribute__((ext_vector_type(4)));

// module-owned weight caches (written by prep each launch):
// g_W3: W_k/W_qk slice in MFMA fragment order: [s=8][ut=16][lane=64][j=8] bf16 =128KB
//   g_W3[((s*16+ut)*64+lane)*8+j] = bf16(W_hide[(128 + s*32 + (lane>>4)*8 + j)*256
//                                               + ut*16 + (lane&15)])
// g_Wq_c: W_q slice c-major (== W_hide layout, rows 0..127), bf16 = 64KB
__device__ __bf16 g_W3[65536];
__device__ __bf16 g_Wq_c[128 * 256];

// ---- prep: build g_Wq_c (linear copy+cast) and g_W3 (fragment shuffle) ----
__global__ __launch_bounds__(256) void prep_kernel(const float* __restrict__ W_hide) {
  const int bid = blockIdx.x, t = threadIdx.x;
  if (bid < 32) {
    // g_Wq_c: 32768 elems = 128*256 (c<128): same linear layout as W_hide
    const int base = bid * 1024;
#pragma unroll
    for (int i = 0; i < 4; ++i) {
      int idx = base + i * 256 + t;
      g_Wq_c[idx] = (__bf16)W_hide[idx];   // coalesced read & write
    }
  } else {
    // g_W3: 8192 fragments of 8 bf16; one fragment per thread
    const int o = (bid - 32) * 256 + t;          // 0..8191
    const int s = o >> 10, ut = (o >> 6) & 15, lane = o & 63;
    const int quad = lane >> 4, m = lane & 15;
    const int u = ut * 16 + m;
    const int c0 = 128 + s * 32 + quad * 8;
    bf16x8 v;
#pragma unroll
    for (int j = 0; j < 8; ++j)
      v[j] = (__bf16)W_hide[(c0 + j) * 256 + u];  // scattered 4B reads (tiny kernel)
    *(bf16x8*)&g_W3[o * 8] = v;                   // coalesced 16B write
  }
}

// ---- main: one block (4 waves, 256 threads) per b ----
__global__ __launch_bounds__(256) void din_main_kernel(
    const int* __restrict__ qid_item, const int* __restrict__ qid_cate,
    const int* __restrict__ seq_item, const int* __restrict__ seq_cate,
    const int* __restrict__ mask,
    const float* __restrict__ emb_item,
    const float* __restrict__ emb_cate,
    const float* __restrict__ b_hide,  // [256]
    const float* __restrict__ W_out,   // [256]
    const float* __restrict__ b_out,   // [1]
    float* __restrict__ out) {
  __shared__ alignas(16) __bf16 Kb[LP * KSTR];   // bf16(K)
  __shared__ alignas(16) __bf16 A2[LP * KSTR];   // bf16(K*q)
  __shared__ alignas(16) float qrowf[E_DIM];     // fp32 q
  __shared__ alignas(16) float qv2[2][U_DIM];    // split-K partials of b_hide+q·W_q
  __shared__ float mask_f[LP];
  __shared__ float scpart[4][LP];                // per-wave u-partial scores
  __shared__ float scores_s[LP];
  __shared__ float outp[4][E_DIM];               // per-wave l-partial outputs

  const int b = blockIdx.x;
  const int t = threadIdx.x;
  const int r = t >> 2, q4 = t & 3;
  const int col0 = q4 * 32;   // this thread's 32 columns of [item|cate]

  // ---- phase 1: gather K rows (fp32) into regs, cast to LDS bf16 ----
  float4 kv[8];
  if (r < L_SEQ) {
    int id = (q4 < 2) ? seq_item[b * L_SEQ + r] : seq_cate[b * L_SEQ + r];
    if ((unsigned)id >= (unsigned)V_SZ) id = 0;   // insurance
    const float4* s4 = (const float4*)(((q4 < 2) ? emb_item : emb_cate)
                                       + (size_t)id * D_EMB + (q4 & 1) * 32);
#pragma unroll
    for (int i = 0; i < 8; ++i) kv[i] = s4[i];
  } else {
#pragma unroll
    for (int i = 0; i < 8; ++i) kv[i] = make_float4(0.f, 0.f, 0.f, 0.f);
  }
#pragma unroll
  for (int i = 0; i < 8; ++i) {
    bf16x4 h4 = {(__bf16)kv[i].x, (__bf16)kv[i].y, (__bf16)kv[i].z, (__bf16)kv[i].w};
    *(bf16x4*)&Kb[r * KSTR + col0 + i * 4] = h4;   // 8B store, aligned
  }
  if (t < 4) {   // q row: 4 threads x 32 floats
    int id = (t < 2) ? qid_item[b] : qid_cate[b];
    if ((unsigned)id >= (unsigned)V_SZ) id = 0;
    const float4* s4 = (const float4*)(((t < 2) ? emb_item : emb_cate)
                                       + (size_t)id * D_EMB + (t & 1) * 32);
    float4* d4 = (float4*)&qrowf[t * 32];
#pragma unroll
    for (int i = 0; i < 8; ++i) d4[i] = s4[i];
  }
  if (t < LP) mask_f[t] = (t < L_SEQ && mask[b * L_SEQ + t] != 0) ? 1.0f : 0.0f;
  __syncthreads();

  // ---- phase 2: A2 = bf16(K * q) from fp32 regs (single rounding) ----
#pragma unroll
  for (int i = 0; i < 8; ++i) {
    const float* qp = &qrowf[col0 + i * 4];
    bf16x4 h4 = {(__bf16)(kv[i].x * qp[0]), (__bf16)(kv[i].y * qp[1]),
                 (__bf16)(kv[i].z * qp[2]), (__bf16)(kv[i].w * qp[3])};
    *(bf16x4*)&A2[r * KSTR + col0 + i * 4] = h4;
  }
  __syncthreads();

  // ---- phase 3a: qv2[ch][u] partials, coalesced c-major W_q reads ----
  {
    const int ch = t >> 7;               // c-half: [0,64) or [64,128)
    const int u0 = (t & 127) * 2;        // this thread owns u0, u0+1
    float a0 = ch ? 0.f : b_hide[u0];
    float a1 = ch ? 0.f : b_hide[u0 + 1];
    const __bf16* wp = &g_Wq_c[(ch * 64) * 256 + u0];
    const float* qp = &qrowf[ch * 64];
#pragma unroll 16
    for (int cc = 0; cc < 64; ++cc) {
      bf16x2 w2 = *(const bf16x2*)(wp + cc * 256);  // lane-consecutive 4B
      float qc = qp[cc];                            // wave-uniform LDS broadcast
      a0 += qc * (float)w2[0];
      a1 += qc * (float)w2[1];
    }
    qv2[ch][u0] = a0;
    qv2[ch][u0 + 1] = a1;
  }

  // ---- phase 3b: swapped MFMA. M=u (64/wave, 4 tiles), N=l (64, 4 tiles),
  //      K=256 (8 steps). A-op = g_W3 fragments (coalesced), B-op = Kb/A2 (LDS).
  const int wave = t >> 6, lane = t & 63;
  const int m = lane & 15, quad = lane >> 4;
  f32x4 acc[4][4];
#pragma unroll
  for (int mt = 0; mt < 4; ++mt)
#pragma unroll
    for (int nt = 0; nt < 4; ++nt) acc[mt][nt] = (f32x4){0.f, 0.f, 0.f, 0.f};

#pragma unroll
  for (int s = 0; s < 8; ++s) {
    const __bf16* Bb = (s < 4) ? Kb : A2;
    const int klocal = (s & 3) * 32 + quad * 8;
    bf16x8 wfr[4], kfr[4];
#pragma unroll
    for (int mt = 0; mt < 4; ++mt) {
      // fragment-ordered: lane-consecutive 16B -> fully coalesced 1KB/instr
      const int o = s * 1024 + (wave * 4 + mt) * 64 + lane;
      wfr[mt] = *(const bf16x8*)&g_W3[o * 8];
    }
#pragma unroll
    for (int nt = 0; nt < 4; ++nt)
      kfr[nt] = *(const bf16x8*)&Bb[(nt * 16 + m) * KSTR + klocal];
#pragma unroll
    for (int mt = 0; mt < 4; ++mt)
#pragma unroll
      for (int nt = 0; nt < 4; ++nt)
        acc[mt][nt] = __builtin_amdgcn_mfma_f32_16x16x32_bf16(
            wfr[mt], kfr[nt], acc[mt][nt], 0, 0, 0);
  }
  __syncthreads();   // qv2 ready for cross-thread reads

  // ---- epilogue: C[u,l]: u = wave*64+mt*16+quad*4+rg (in-lane), l = nt*16+m.
  //      part[nt] = sum_u relu(C+qv[u])*W_out[u]  — u-reduce is in-lane + quads.
  float qv4[4][4], wo4[4][4];
#pragma unroll
  for (int mt = 0; mt < 4; ++mt) {
    const int u0 = wave * 64 + mt * 16 + quad * 4;
    f32x4 qa = *(const f32x4*)&qv2[0][u0];      // lane-uniform/16 broadcast
    f32x4 qb = *(const f32x4*)&qv2[1][u0];
    float4 ww = *(const float4*)&W_out[u0];     // 4 lines/wave, L2-resident
    qv4[mt][0] = qa[0] + qb[0]; qv4[mt][1] = qa[1] + qb[1];
    qv4[mt][2] = qa[2] + qb[2]; qv4[mt][3] = qa[3] + qb[3];
    wo4[mt][0] = ww.x;  wo4[mt][1] = ww.y;  wo4[mt][2] = ww.z;  wo4[mt][3] = ww.w;
  }
  float part[4];
#pragma unroll
  for (int nt = 0; nt < 4; ++nt) {
    float sum = 0.f;
#pragma unroll
    for (int mt = 0; mt < 4; ++mt)
#pragma unroll
      for (int rg = 0; rg < 4; ++rg) {
        float h = acc[mt][nt][rg] + qv4[mt][rg];
        h = fmaxf(h, 0.f);
        sum += h * wo4[mt][rg];
      }
    part[nt] = sum;
  }
#pragma unroll
  for (int nt = 0; nt < 4; ++nt) {   // reduce over 4 quads
    part[nt] += __shfl_xor(part[nt], 16, 64);
    part[nt] += __shfl_xor(part[nt], 32, 64);
  }
  if (lane < 16) {
#pragma unroll
    for (int nt = 0; nt < 4; ++nt)
      scpart[wave][nt * 16 + lane] = part[nt];   // l = nt*16+lane
  }
  __syncthreads();

  // ---- scores (t<64), then wave-parallel out partials ----
  if (t < LP) {
    float s = scpart[0][t] + scpart[1][t] + scpart[2][t] + scpart[3][t]
            + b_out[0];
    scores_s[t] = s * mask_f[t];
  }
  __syncthreads();
  // wave w accumulates rows [w*16, w*16+16); lane covers e = 2*lane, 2*lane+1
  {
    const int e2 = lane * 2;
    float o0 = 0.f, o1 = 0.f;
#pragma unroll
    for (int i = 0; i < 16; ++i) {
      const int l = wave * 16 + i;
      const float sc = scores_s[l];                       // broadcast
      bf16x2 kk = *(const bf16x2*)&Kb[l * KSTR + e2];     // b32 pair, 2-way banks
      o0 += sc * (float)kk[0];
      o1 += sc * (float)kk[1];
    }
    outp[wave][e2]     = o0;
    outp[wave][e2 + 1] = o1;
  }
  __syncthreads();
  if (t < E_DIM) {
    float o = outp[0][t] + outp[1][t] + outp[2][t] + outp[3][t];
    out[(size_t)b * E_DIM + t] = o;
  }
}

extern "C" void kernel_launch(void* const* d_in, const int* in_sizes, int n_in,
                              void* d_out, int out_size, void* d_ws, size_t ws_size,
                              hipStream_t stream) {
  const int* qid_item = (const int*)d_in[0];
  const int* qid_cate = (const int*)d_in[1];
  const int* seq_item = (const int*)d_in[2];
  const int* seq_cate = (const int*)d_in[3];
  const int* mask     = (const int*)d_in[4];
  const float* emb_item = (const float*)d_in[5];
  const float* emb_cate = (const float*)d_in[6];
  const float* W_hide   = (const float*)d_in[7];
  const float* b_hide   = (const float*)d_in[8];
  const float* W_out    = (const float*)d_in[9];
  const float* b_out    = (const float*)d_in[10];
  float* out = (float*)d_out;

  (void)d_ws; (void)ws_size;  // intentionally unused

  prep_kernel<<<64, 256, 0, stream>>>(W_hide);
  din_main_kernel<<<4096, 256, 0, stream>>>(qid_item, qid_cate, seq_item, seq_cate,
                                            mask, emb_item, emb_cate,
                                            b_hide, W_out, b_out, out);
}